// Round 2
// 250.901 us; speedup vs baseline: 1.0204x; 1.0204x over previous
//
#include <hip/hip_runtime.h>
#include <hip/hip_bf16.h>

using bf16 = __hip_bfloat16;
typedef __attribute__((ext_vector_type(8))) short bf16x8;
typedef __attribute__((ext_vector_type(4))) float f32x4;

// Problem constants
constexpr int S = 8, I = 64, M = 256, N = 16384;
constexpr int SM = S * M;       // 2048
constexpr int MODROW = S * I;   // 512  elements per modulation row
constexpr int OUTROW = S * M;   // 2048 fp32 elements per output row
constexpr int TILES = 8;        // 16-row n-tiles per wave in the main kernel

// Gate scale constants folded into Weff/beff:
//   i,f,o: k = -log2(e)    => sigmoid(x) = rcp(1 + exp2(k*x))
//   g:     k = -2*log2(e)  => tanh(x)    = fma(2, rcp(1 + exp2(k*x)), -1)
constexpr float LOG2E = 1.4426950408889634f;
constexpr float KSIG  = -LOG2E;
constexpr float KTANH = -2.0f * LOG2E;

__device__ __forceinline__ short f2bf_s(float f) {
    union { bf16 b; short s; } u; u.b = __float2bfloat16(f); return u.s;
}
// load 8 consecutive fp32 -> bf16x8 fragment slice (RNE)
__device__ __forceinline__ bf16x8 cvt8(const float* p) {
    const f32x4 x = ((const f32x4*)p)[0];
    const f32x4 y = ((const f32x4*)p)[1];
    bf16x8 r;
    r[0] = f2bf_s(x[0]); r[1] = f2bf_s(x[1]); r[2] = f2bf_s(x[2]); r[3] = f2bf_s(x[3]);
    r[4] = f2bf_s(y[0]); r[5] = f2bf_s(y[1]); r[6] = f2bf_s(y[2]); r[7] = f2bf_s(y[3]);
    return r;
}

__device__ __forceinline__ float exp2_f(float x) {
#if __has_builtin(__builtin_amdgcn_exp2f)
    return __builtin_amdgcn_exp2f(x);
#else
    return __expf(x * 0.6931471805599453f);
#endif
}
__device__ __forceinline__ float rcp_f(float x) { return __builtin_amdgcn_rcpf(x); }
// y is already scaled by KSIG:  sigmoid
__device__ __forceinline__ float sig2_f(float y)  { return rcp_f(1.f + exp2_f(y)); }
// y is already scaled by KTANH: tanh
__device__ __forceinline__ float tanh2_f(float y) { return fmaf(2.f, rcp_f(1.f + exp2_f(y)), -1.f); }

// ---------------------------------------------------------------------------
// Kernel 1 (fused prep):
//   blocks [0, PRE_BLOCKS):      Weff/beff precompute (1 wave-unit per wave)
//   blocks [PRE_BLOCKS, +4096):  mod fp32 -> bf16 conversion, 8 elems/thread
// The two halves are independent and run concurrently instead of serially.
//
//   Weff[s][m][g][k] = kg * sum_j WG[s][m][j]*Wx[s][j][k]   (bf16)
//   beff[g][sm]      = kg * (bG + WG[:, :256]·bx + WG[:, 256:]·h0)  (fp32)
// ---------------------------------------------------------------------------
constexpr int PRE_BLOCKS = 512;                      // 512 * 4 waves = 2048 units
constexpr int CVT_BLOCKS = (N * MODROW) / (8 * 256); // 4096

__global__ __launch_bounds__(256) void prep_fused(
    const float* __restrict__ mod, bf16* __restrict__ modb,
    const float* __restrict__ Wx, const float* __restrict__ bx,
    const float* __restrict__ Wi, const float* __restrict__ bi,
    const float* __restrict__ Wf, const float* __restrict__ bfv,
    const float* __restrict__ Wg, const float* __restrict__ bg,
    const float* __restrict__ Wo, const float* __restrict__ bo,
    const float* __restrict__ h0,
    bf16* __restrict__ Weff, float* __restrict__ beff)
{
    if (blockIdx.x >= PRE_BLOCKS) {
        // ------- conversion part: read-once fp32 -> bf16 (nontemporal loads)
        const size_t i =
            ((size_t)(blockIdx.x - PRE_BLOCKS) * 256 + threadIdx.x) * 8;
        const f32x4 x = __builtin_nontemporal_load((const f32x4*)(mod + i));
        const f32x4 y = __builtin_nontemporal_load((const f32x4*)(mod + i) + 1);
        bf16x8 r;
        r[0] = f2bf_s(x[0]); r[1] = f2bf_s(x[1]); r[2] = f2bf_s(x[2]); r[3] = f2bf_s(x[3]);
        r[4] = f2bf_s(y[0]); r[5] = f2bf_s(y[1]); r[6] = f2bf_s(y[2]); r[7] = f2bf_s(y[3]);
        *(bf16x8*)(modb + i) = r;
        return;
    }

    // ------- precompute part: one old 64-thread block per wave
    // readfirstlane: force unit (and thus all weight-row pointers) into SGPRs
    const int unit = __builtin_amdgcn_readfirstlane(
        blockIdx.x * 4 + (threadIdx.x >> 6));
    const int k  = threadIdx.x & 63;
    const int mc = unit & 63;
    const int g  = (unit >> 6) & 3;
    const int s  = unit >> 8;

    const float* WG = (g == 0) ? Wi : (g == 1) ? Wf : (g == 2) ? Wg : Wo;
    const float* bG = (g == 0) ? bi : (g == 1) ? bfv : (g == 2) ? bg : bo;
    const float  kg = (g == 2) ? KTANH : KSIG;

    const int sm0 = s * 256 + mc * 4;
    const float* w0 = WG + (size_t)(sm0 + 0) * 512;
    const float* w1 = WG + (size_t)(sm0 + 1) * 512;
    const float* w2 = WG + (size_t)(sm0 + 2) * 512;
    const float* w3 = WG + (size_t)(sm0 + 3) * 512;
    const float* wxs = Wx + (size_t)s * (256 * 64) + k;

    float a0 = 0.f, a1 = 0.f, a2 = 0.f, a3 = 0.f;
    for (int j = 0; j < 256; j += 8) {
#pragma unroll
        for (int u = 0; u < 8; ++u) {
            const float wx = wxs[(size_t)(j + u) * 64];
            a0 = fmaf(w0[j + u], wx, a0);
            a1 = fmaf(w1[j + u], wx, a1);
            a2 = fmaf(w2[j + u], wx, a2);
            a3 = fmaf(w3[j + u], wx, a3);
        }
    }
    Weff[((size_t)(sm0 + 0) * 4 + g) * 64 + k] = __float2bfloat16(a0 * kg);
    Weff[((size_t)(sm0 + 1) * 4 + g) * 64 + k] = __float2bfloat16(a1 * kg);
    Weff[((size_t)(sm0 + 2) * 4 + g) * 64 + k] = __float2bfloat16(a2 * kg);
    Weff[((size_t)(sm0 + 3) * 4 + g) * 64 + k] = __float2bfloat16(a3 * kg);

    float b0 = 0.f, b1 = 0.f, b2 = 0.f, b3 = 0.f;
#pragma unroll
    for (int t = 0; t < 4; ++t) {
        const int j = k + t * 64;
        const float xb = bx[(s << 8) + j];
        const float xh = h0[(s << 8) + j];
        b0 = fmaf(w0[j], xb, b0); b0 = fmaf(w0[256 + j], xh, b0);
        b1 = fmaf(w1[j], xb, b1); b1 = fmaf(w1[256 + j], xh, b1);
        b2 = fmaf(w2[j], xb, b2); b2 = fmaf(w2[256 + j], xh, b2);
        b3 = fmaf(w3[j], xb, b3); b3 = fmaf(w3[256 + j], xh, b3);
    }
#pragma unroll
    for (int off = 32; off > 0; off >>= 1) {
        b0 += __shfl_down(b0, off);
        b1 += __shfl_down(b1, off);
        b2 += __shfl_down(b2, off);
        b3 += __shfl_down(b3, off);
    }
    if (k == 0) {
        beff[g * SM + sm0 + 0] = (b0 + bG[sm0 + 0]) * kg;
        beff[g * SM + sm0 + 1] = (b1 + bG[sm0 + 1]) * kg;
        beff[g * SM + sm0 + 2] = (b2 + bG[sm0 + 2]) * kg;
        beff[g * SM + sm0 + 3] = (b3 + bG[sm0 + 3]) * kg;
    }
}

// ---------------------------------------------------------------------------
// Kernel 2 (bf16-B): A = Weff (D rows = features), B = pre-converted bf16 mod.
// Bias folded into MFMA acc init; gate scales pre-folded -> exp2-direct
// epilogue (21 VALU/row instead of 25). Nontemporal out stores (never re-read).
// ---------------------------------------------------------------------------
__global__ __launch_bounds__(256) void lstm_main_bf(
    const bf16* __restrict__ modb, const float* __restrict__ c0,
    const bf16* __restrict__ Weff, const float* __restrict__ beff,
    float* __restrict__ out)
{
    const int wave = threadIdx.x >> 6;
    const int lane = threadIdx.x & 63;
    const int quad = lane >> 4;
    const int col  = lane & 15;

    const int s  = blockIdx.y >> 2;
    const int mq = blockIdx.y & 3;
    const int m0 = mq * 64 + wave * 16;
    const int sm_tile = s * 256 + m0;

    // A fragments: A[m = lane&15][k = quad*8 + j]; Weff layout [s][m][g][k]
    const bf16* abase = Weff + ((size_t)(sm_tile + col) * 4) * 64 + quad * 8;
    bf16x8 afrag[4][2];
#pragma unroll
    for (int g = 0; g < 4; ++g) {
        afrag[g][0] = *(const bf16x8*)(abase + (size_t)g * 64);
        afrag[g][1] = *(const bf16x8*)(abase + (size_t)g * 64 + 32);
    }

    // n-invariant constants: this thread owns m = sm4 + {0..3}
    const int sm4 = sm_tile + quad * 4;
    const f32x4 c0v = *(const f32x4*)(c0 + sm4);
    f32x4 bias[4];
#pragma unroll
    for (int g = 0; g < 4; ++g)
        bias[g] = *(const f32x4*)(beff + g * SM + sm4);

    const int nbase = blockIdx.x * (16 * TILES);
    const bf16* brow0 = modb + (size_t)(nbase + col) * MODROW + s * I + quad * 8;

    bf16x8 b0 = *(const bf16x8*)(brow0);
    bf16x8 b1 = *(const bf16x8*)(brow0 + 32);

#pragma unroll
    for (int t = 0; t < TILES; ++t) {
        bf16x8 nb0, nb1;
        if (t + 1 < TILES) {
            const bf16* brow = brow0 + (size_t)(t + 1) * 16 * MODROW;
            nb0 = *(const bf16x8*)(brow);
            nb1 = *(const bf16x8*)(brow + 32);
        }

        f32x4 acc[4];
#pragma unroll
        for (int g = 0; g < 4; ++g) {
            f32x4 c = bias[g];   // bias pre-loaded into accumulator
            c = __builtin_amdgcn_mfma_f32_16x16x32_bf16(afrag[g][0], b0, c, 0, 0, 0);
            c = __builtin_amdgcn_mfma_f32_16x16x32_bf16(afrag[g][1], b1, c, 0, 0, 0);
            acc[g] = c;
        }

        const int n = nbase + t * 16 + col;
        f32x4 hv;
#pragma unroll
        for (int r = 0; r < 4; ++r) {
            const float iv = sig2_f(acc[0][r]);
            const float fv = sig2_f(acc[1][r]);
            const float gv = tanh2_f(acc[2][r]);
            const float ov = sig2_f(acc[3][r]);
            const float cc = fmaf(fv, c0v[r], iv * gv);
            hv[r] = ov * tanh2_f(cc * KTANH);
        }
        __builtin_nontemporal_store(hv, (f32x4*)(out + (size_t)n * OUTROW + sm4));

        if (t + 1 < TILES) { b0 = nb0; b1 = nb1; }
    }
}

// ---------------------------------------------------------------------------
// Kernel 2 fallback (f32-B, inline cvt) — used only if ws too small for modb.
// ---------------------------------------------------------------------------
__global__ __launch_bounds__(256) void lstm_main_f32(
    const float* __restrict__ mod, const float* __restrict__ c0,
    const bf16* __restrict__ Weff, const float* __restrict__ beff,
    float* __restrict__ out)
{
    const int wave = threadIdx.x >> 6;
    const int lane = threadIdx.x & 63;
    const int quad = lane >> 4;
    const int col  = lane & 15;

    const int s  = blockIdx.y >> 2;
    const int mq = blockIdx.y & 3;
    const int m0 = mq * 64 + wave * 16;
    const int sm_tile = s * 256 + m0;

    const bf16* abase = Weff + ((size_t)(sm_tile + col) * 4) * 64 + quad * 8;
    bf16x8 afrag[4][2];
#pragma unroll
    for (int g = 0; g < 4; ++g) {
        afrag[g][0] = *(const bf16x8*)(abase + (size_t)g * 64);
        afrag[g][1] = *(const bf16x8*)(abase + (size_t)g * 64 + 32);
    }

    const int sm4 = sm_tile + quad * 4;
    const f32x4 c0v = *(const f32x4*)(c0 + sm4);
    f32x4 bias[4];
#pragma unroll
    for (int g = 0; g < 4; ++g)
        bias[g] = *(const f32x4*)(beff + g * SM + sm4);

    const int nbase = blockIdx.x * (16 * TILES);
    const float* brow0 = mod + (size_t)(nbase + col) * MODROW + s * I + quad * 8;

    bf16x8 b0 = cvt8(brow0);
    bf16x8 b1 = cvt8(brow0 + 32);

#pragma unroll
    for (int t = 0; t < TILES; ++t) {
        bf16x8 nb0, nb1;
        if (t + 1 < TILES) {
            const float* brow = brow0 + (size_t)(t + 1) * 16 * MODROW;
            nb0 = cvt8(brow);
            nb1 = cvt8(brow + 32);
        }
        f32x4 acc[4];
#pragma unroll
        for (int g = 0; g < 4; ++g) {
            f32x4 c = bias[g];
            c = __builtin_amdgcn_mfma_f32_16x16x32_bf16(afrag[g][0], b0, c, 0, 0, 0);
            c = __builtin_amdgcn_mfma_f32_16x16x32_bf16(afrag[g][1], b1, c, 0, 0, 0);
            acc[g] = c;
        }
        const int n = nbase + t * 16 + col;
        f32x4 hv;
#pragma unroll
        for (int r = 0; r < 4; ++r) {
            const float iv = sig2_f(acc[0][r]);
            const float fv = sig2_f(acc[1][r]);
            const float gv = tanh2_f(acc[2][r]);
            const float ov = sig2_f(acc[3][r]);
            const float cc = fmaf(fv, c0v[r], iv * gv);
            hv[r] = ov * tanh2_f(cc * KTANH);
        }
        __builtin_nontemporal_store(hv, (f32x4*)(out + (size_t)n * OUTROW + sm4));
        if (t + 1 < TILES) { b0 = nb0; b1 = nb1; }
    }
}

extern "C" void kernel_launch(void* const* d_in, const int* in_sizes, int n_in,
                              void* d_out, int out_size, void* d_ws, size_t ws_size,
                              hipStream_t stream) {
    const float* mod = (const float*)d_in[0];
    const float* h0  = (const float*)d_in[1];
    const float* c0  = (const float*)d_in[2];
    const float* Wx  = (const float*)d_in[3];
    const float* bx  = (const float*)d_in[4];
    const float* Wi  = (const float*)d_in[5];
    const float* bi  = (const float*)d_in[6];
    const float* Wf  = (const float*)d_in[7];
    const float* bfv = (const float*)d_in[8];
    const float* Wg  = (const float*)d_in[9];
    const float* bg  = (const float*)d_in[10];
    const float* Wo  = (const float*)d_in[11];
    const float* bo  = (const float*)d_in[12];
    float* out = (float*)d_out;

    // ws layout: Weff bf16 (1 MiB) | beff fp32 (32 KiB) | modb bf16 (16 MiB)
    const size_t weff_b = (size_t)SM * 4 * 64 * sizeof(bf16);   // 1,048,576
    const size_t beff_b = (size_t)4 * SM * sizeof(float);       //    32,768
    const size_t modb_b = (size_t)N * MODROW * sizeof(bf16);    // 16,777,216
    bf16*  Weff = (bf16*)d_ws;
    float* beff = (float*)((char*)d_ws + weff_b);
    bf16*  modb = (bf16*)((char*)d_ws + weff_b + beff_b);

    if (ws_size >= weff_b + beff_b + modb_b) {
        // fused prep: precompute (512 blocks) + conversion (4096 blocks), concurrent
        prep_fused<<<PRE_BLOCKS + CVT_BLOCKS, 256, 0, stream>>>(
            mod, modb, Wx, bx, Wi, bi, Wf, bfv, Wg, bg, Wo, bo, h0, Weff, beff);
        lstm_main_bf<<<dim3(N / (16 * TILES), S * 4), 256, 0, stream>>>(
            modb, c0, Weff, beff, out);
    } else {
        // precompute only (no conversion blocks launched)
        prep_fused<<<PRE_BLOCKS, 256, 0, stream>>>(
            mod, modb, Wx, bx, Wi, bi, Wf, bfv, Wg, bg, Wo, bo, h0, Weff, beff);
        lstm_main_f32<<<dim3(N / (16 * TILES), S * 4), 256, 0, stream>>>(
            mod, c0, Weff, beff, out);
    }
}